// Round 1
// baseline (437.526 us; speedup 1.0000x reference)
//
#include <hip/hip_runtime.h>
#include <hip/hip_bf16.h>

typedef __attribute__((ext_vector_type(8))) short bf16x8;
typedef __attribute__((ext_vector_type(4))) float f32x4;

#define DEVINL __device__ __forceinline__

static DEVINL ushort f2b(float f) {
    union { float f; unsigned int u; } v; v.f = f;
    unsigned int u = v.u;
    unsigned int r = (u + 0x7FFFu + ((u >> 16) & 1u)) >> 16;
    return (ushort)r;
}

// ---------------- cast kernels ----------------
// Wcat[n][k], n in [0,4096): rows 0-1023 = Wq*0.125, 1024-2047 = Wk, 2048-3071 = Wv, 3072-4095 = Wp
__global__ void cast_w_kernel(const float* __restrict__ Wq, const float* __restrict__ Wk,
                              const float* __restrict__ Wv, const float* __restrict__ Wp,
                              ushort* __restrict__ out) {
    int idx = blockIdx.x * blockDim.x + threadIdx.x;   // one float4 per thread
    int col4 = idx & 255;          // 1024/4
    int row  = idx >> 8;           // 0..4095
    int which = row >> 10;
    int r = row & 1023;
    const float* src = (which == 0) ? Wq : (which == 1) ? Wk : (which == 2) ? Wv : Wp;
    float s = (which == 0) ? 0.125f : 1.0f;
    float4 v = ((const float4*)src)[r * 256 + col4];
    ushort4 o;
    o.x = f2b(v.x * s); o.y = f2b(v.y * s); o.z = f2b(v.z * s); o.w = f2b(v.w * s);
    ((ushort4*)out)[idx] = o;
}

__global__ void cast_x_kernel(const float* __restrict__ x, ushort* __restrict__ out) {
    int idx = blockIdx.x * blockDim.x + threadIdx.x;   // one float4 per thread
    float4 v = ((const float4*)x)[idx];
    ushort4 o;
    o.x = f2b(v.x); o.y = f2b(v.y); o.z = f2b(v.z); o.w = f2b(v.w);
    ((ushort4*)out)[idx] = o;
}

// ---------------- generic GEMM: C[m][n] = sum_k A[m][k]*B[n][k] (+bias) ----------------
template<bool BF16_OUT>
__global__ __launch_bounds__(256) void gemm_bt_kernel(const ushort* __restrict__ A,
                                                      const ushort* __restrict__ B,
                                                      void* __restrict__ Cv,
                                                      const float* __restrict__ bias,
                                                      int M, int N, int K) {
    __shared__ ushort Al[128][72];
    __shared__ ushort Bl[128][72];
    const int tid = threadIdx.x;
    const int m0 = blockIdx.y * 128, n0 = blockIdx.x * 128;
    const int lane = tid & 63, wid = tid >> 6;
    const int wm = (wid >> 1) * 64, wn = (wid & 1) * 64;
    const int lr = lane & 15, lg = lane >> 4;

    f32x4 acc[4][4];
    #pragma unroll
    for (int i = 0; i < 4; ++i)
        #pragma unroll
        for (int j = 0; j < 4; ++j)
            acc[i][j] = (f32x4){0.f, 0.f, 0.f, 0.f};

    const int arow = tid >> 3;
    const int ac8  = (tid & 7) * 8;
    const int nkt = K >> 6;
    for (int kt = 0; kt < nkt; ++kt) {
        __syncthreads();
        #pragma unroll
        for (int i = 0; i < 4; ++i) {
            int row = arow + i * 32;
            *(uint4*)&Al[row][ac8] = *(const uint4*)&A[(size_t)(m0 + row) * K + kt * 64 + ac8];
            *(uint4*)&Bl[row][ac8] = *(const uint4*)&B[(size_t)(n0 + row) * K + kt * 64 + ac8];
        }
        __syncthreads();
        #pragma unroll
        for (int kk = 0; kk < 64; kk += 32) {
            bf16x8 af[4], bfr[4];
            #pragma unroll
            for (int mi = 0; mi < 4; ++mi)
                af[mi] = *(const bf16x8*)&Al[wm + mi * 16 + lr][kk + lg * 8];
            #pragma unroll
            for (int ni = 0; ni < 4; ++ni)
                bfr[ni] = *(const bf16x8*)&Bl[wn + ni * 16 + lr][kk + lg * 8];
            #pragma unroll
            for (int mi = 0; mi < 4; ++mi)
                #pragma unroll
                for (int ni = 0; ni < 4; ++ni)
                    acc[mi][ni] = __builtin_amdgcn_mfma_f32_16x16x32_bf16(af[mi], bfr[ni], acc[mi][ni], 0, 0, 0);
        }
    }
    // epilogue: D row = (lane>>4)*4 + r, col = lane&15
    #pragma unroll
    for (int mi = 0; mi < 4; ++mi) {
        #pragma unroll
        for (int r = 0; r < 4; ++r) {
            int gm = m0 + wm + mi * 16 + lg * 4 + r;
            #pragma unroll
            for (int ni = 0; ni < 4; ++ni) {
                int gn = n0 + wn + ni * 16 + lr;
                float val = acc[mi][ni][r];
                if (BF16_OUT) {
                    ((ushort*)Cv)[(size_t)gm * N + gn] = f2b(val);
                } else {
                    ((float*)Cv)[(size_t)gm * N + gn] = val + bias[gn];
                }
            }
        }
    }
}

// ---------------- V transpose: Vt[nv][t] = QKV[t][2048+nv] ----------------
__global__ void transpose_v_kernel(const ushort* __restrict__ QKV, ushort* __restrict__ Vt) {
    __shared__ ushort tile[32][33];
    int t0 = blockIdx.x * 32;
    int n0 = blockIdx.y * 32;
    int tx = threadIdx.x, ty = threadIdx.y; // (32,8)
    #pragma unroll
    for (int i = 0; i < 4; ++i) {
        int row = ty + i * 8;
        tile[row][tx] = QKV[(size_t)(t0 + row) * 3072 + 2048 + n0 + tx];
    }
    __syncthreads();
    #pragma unroll
    for (int i = 0; i < 4; ++i) {
        int row = ty + i * 8;
        Vt[(size_t)(n0 + row) * 8192 + t0 + tx] = tile[tx][row];
    }
}

// ---------------- causal flash attention ----------------
// QKV [8192][3072] bf16 (Q pre-scaled by 0.125), Vt [1024][8192] bf16, O [8192][1024] bf16
__global__ __launch_bounds__(256) void attn_kernel(const ushort* __restrict__ QKV,
                                                   const ushort* __restrict__ Vt,
                                                   ushort* __restrict__ O) {
    __shared__ ushort Kl[32][72];
    __shared__ ushort Vl[64][40];
    __shared__ ushort Pl[4][16][40];

    const int q0 = blockIdx.x * 64;
    const int bh = blockIdx.y, b = bh >> 4, h = bh & 15;
    const int tid = threadIdx.x, lane = tid & 63, w = tid >> 6;
    const int lr = lane & 15, lg = lane >> 4;
    const int qbase = q0 + w * 16;

    const ushort* qptr = QKV + (size_t)(b * 2048 + qbase + lr) * 3072 + h * 64 + lg * 8;
    bf16x8 qf0 = *(const bf16x8*)qptr;
    bf16x8 qf1 = *(const bf16x8*)(qptr + 32);

    f32x4 o[4];
    #pragma unroll
    for (int i = 0; i < 4; ++i) o[i] = (f32x4){0.f, 0.f, 0.f, 0.f};
    float mrow[4] = {-INFINITY, -INFINITY, -INFINITY, -INFINITY};
    float lrow[4] = {0.f, 0.f, 0.f, 0.f};

    const int kr = tid >> 3, kc = (tid & 7) * 8;
    const int vr = tid >> 2, vc = (tid & 3) * 8;
    const size_t kbase = (size_t)(b * 2048) * 3072 + 1024 + h * 64;
    const size_t vbase = (size_t)(h * 64) * 8192 + b * 2048;

    for (int kv = 0; kv < q0 + 64; kv += 32) {
        *(uint4*)&Kl[kr][kc] = *(const uint4*)&QKV[kbase + (size_t)(kv + kr) * 3072 + kc];
        *(uint4*)&Vl[vr][vc] = *(const uint4*)&Vt[vbase + (size_t)vr * 8192 + kv + vc];
        __syncthreads();

        const bool act = (kv <= qbase + 15);
        if (act) {
            f32x4 s0 = (f32x4){0.f, 0.f, 0.f, 0.f};
            f32x4 s1 = (f32x4){0.f, 0.f, 0.f, 0.f};
            bf16x8 k00 = *(const bf16x8*)&Kl[lr][lg * 8];
            bf16x8 k01 = *(const bf16x8*)&Kl[lr][32 + lg * 8];
            bf16x8 k10 = *(const bf16x8*)&Kl[16 + lr][lg * 8];
            bf16x8 k11 = *(const bf16x8*)&Kl[16 + lr][32 + lg * 8];
            s0 = __builtin_amdgcn_mfma_f32_16x16x32_bf16(qf0, k00, s0, 0, 0, 0);
            s0 = __builtin_amdgcn_mfma_f32_16x16x32_bf16(qf1, k01, s0, 0, 0, 0);
            s1 = __builtin_amdgcn_mfma_f32_16x16x32_bf16(qf0, k10, s1, 0, 0, 0);
            s1 = __builtin_amdgcn_mfma_f32_16x16x32_bf16(qf1, k11, s1, 0, 0, 0);

            float alpha[4], p0v[4], p1v[4];
            #pragma unroll
            for (int r = 0; r < 4; ++r) {
                int qs = qbase + lg * 4 + r;
                float v0 = (kv + lr <= qs) ? s0[r] : -INFINITY;
                float v1 = (kv + 16 + lr <= qs) ? s1[r] : -INFINITY;
                float mx = fmaxf(v0, v1);
                mx = fmaxf(mx, __shfl_xor(mx, 1));
                mx = fmaxf(mx, __shfl_xor(mx, 2));
                mx = fmaxf(mx, __shfl_xor(mx, 4));
                mx = fmaxf(mx, __shfl_xor(mx, 8));
                float mn = fmaxf(mrow[r], mx);
                float al = __expf(mrow[r] - mn);
                float p0 = __expf(v0 - mn);
                float p1 = __expf(v1 - mn);
                float rs = p0 + p1;
                rs += __shfl_xor(rs, 1);
                rs += __shfl_xor(rs, 2);
                rs += __shfl_xor(rs, 4);
                rs += __shfl_xor(rs, 8);
                lrow[r] = lrow[r] * al + rs;
                mrow[r] = mn;
                alpha[r] = al; p0v[r] = p0; p1v[r] = p1;
            }
            #pragma unroll
            for (int r = 0; r < 4; ++r) {
                Pl[w][lg * 4 + r][lr] = f2b(p0v[r]);
                Pl[w][lg * 4 + r][16 + lr] = f2b(p1v[r]);
            }
            #pragma unroll
            for (int ni = 0; ni < 4; ++ni)
                #pragma unroll
                for (int r = 0; r < 4; ++r)
                    o[ni][r] *= alpha[r];
        }
        __syncthreads();   // P visible wave-wide (and block barrier alignment)
        if (act) {
            bf16x8 pa = *(const bf16x8*)&Pl[w][lr][lg * 8];
            #pragma unroll
            for (int ni = 0; ni < 4; ++ni) {
                bf16x8 vb = *(const bf16x8*)&Vl[ni * 16 + lr][lg * 8];
                o[ni] = __builtin_amdgcn_mfma_f32_16x16x32_bf16(pa, vb, o[ni], 0, 0, 0);
            }
        }
        __syncthreads();   // before next-iter staging overwrites Kl/Vl/Pl
    }

    float inv[4];
    #pragma unroll
    for (int r = 0; r < 4; ++r) inv[r] = 1.0f / lrow[r];
    #pragma unroll
    for (int ni = 0; ni < 4; ++ni) {
        #pragma unroll
        for (int r = 0; r < 4; ++r) {
            size_t idx = (size_t)(b * 2048 + qbase + lg * 4 + r) * 1024 + h * 64 + ni * 16 + lr;
            O[idx] = f2b(o[ni][r] * inv[r]);
        }
    }
}

// ---------------- launch ----------------
extern "C" void kernel_launch(void* const* d_in, const int* in_sizes, int n_in,
                              void* d_out, int out_size, void* d_ws, size_t ws_size,
                              hipStream_t stream) {
    const float* x  = (const float*)d_in[0];
    const float* Wk = (const float*)d_in[1];
    const float* Wq = (const float*)d_in[2];
    const float* Wv = (const float*)d_in[3];
    const float* Wp = (const float*)d_in[4];
    const float* bp = (const float*)d_in[5];
    float* out = (float*)d_out;

    char* ws = (char*)d_ws;
    ushort* Xb   = (ushort*)(ws);                       // 8192x1024 bf16 = 16 MB
    ushort* Wcat = (ushort*)(ws + 16777216);            // 4096x1024 bf16 = 8 MB
    ushort* QKV  = (ushort*)(ws + 25165824);            // 8192x3072 bf16 = 48 MB
    ushort* Vt   = (ushort*)(ws + 75497472);            // 1024x8192 bf16 = 16 MB
    ushort* Obuf = (ushort*)(ws + 92274688);            // 8192x1024 bf16 = 16 MB

    cast_w_kernel<<<4096, 256, 0, stream>>>(Wq, Wk, Wv, Wp, Wcat);
    cast_x_kernel<<<8192, 256, 0, stream>>>(x, Xb);
    gemm_bt_kernel<true><<<dim3(24, 64), 256, 0, stream>>>(Xb, Wcat, QKV, nullptr, 8192, 3072, 1024);
    transpose_v_kernel<<<dim3(256, 32), dim3(32, 8), 0, stream>>>(QKV, Vt);
    attn_kernel<<<dim3(32, 64), 256, 0, stream>>>(QKV, Vt, Obuf);
    gemm_bt_kernel<false><<<dim3(8, 64), 256, 0, stream>>>(Obuf, Wcat + (size_t)3072 * 1024, out, bp, 8192, 1024, 1024);
}

// Round 2
// 237.793 us; speedup vs baseline: 1.8399x; 1.8399x over previous
//
#include <hip/hip_runtime.h>
#include <hip/hip_bf16.h>

typedef __attribute__((ext_vector_type(8))) short bf16x8;
typedef __attribute__((ext_vector_type(4))) float f32x4;

#define DEVINL __device__ __forceinline__

static DEVINL ushort f2b(float f) {
    union { float f; unsigned int u; } v; v.f = f;
    unsigned int u = v.u;
    unsigned int r = (u + 0x7FFFu + ((u >> 16) & 1u)) >> 16;
    return (ushort)r;
}

// swizzled ushort offset of 16B chunk c (0..7) in row of a [*][64]-bf16 linear tile
static DEVINL int swz(int row, int c) {
    return row * 64 + (((c ^ (row & 7)) & 7) << 3);
}

// ---------------- cast kernels ----------------
// Wcat[n][k], n in [0,4096): rows 0-1023 = Wq*0.125, 1024-2047 = Wk, 2048-3071 = Wv, 3072-4095 = Wp
__global__ void cast_w_kernel(const float* __restrict__ Wq, const float* __restrict__ Wk,
                              const float* __restrict__ Wv, const float* __restrict__ Wp,
                              ushort* __restrict__ out) {
    int idx = blockIdx.x * blockDim.x + threadIdx.x;   // one float4 per thread
    int col4 = idx & 255;          // 1024/4
    int row  = idx >> 8;           // 0..4095
    int which = row >> 10;
    int r = row & 1023;
    const float* src = (which == 0) ? Wq : (which == 1) ? Wk : (which == 2) ? Wv : Wp;
    float s = (which == 0) ? 0.125f : 1.0f;
    float4 v = ((const float4*)src)[r * 256 + col4];
    ushort4 o;
    o.x = f2b(v.x * s); o.y = f2b(v.y * s); o.z = f2b(v.z * s); o.w = f2b(v.w * s);
    ((ushort4*)out)[idx] = o;
}

__global__ void cast_x_kernel(const float* __restrict__ x, ushort* __restrict__ out) {
    int idx = blockIdx.x * blockDim.x + threadIdx.x;   // one float4 per thread
    float4 v = ((const float4*)x)[idx];
    ushort4 o;
    o.x = f2b(v.x); o.y = f2b(v.y); o.z = f2b(v.z); o.w = f2b(v.w);
    ((ushort4*)out)[idx] = o;
}

// ---------------- generic GEMM: C[m][n] = sum_k A[m][k]*B[n][k] (+bias) ----------------
template<bool BF16_OUT>
__global__ __launch_bounds__(256) void gemm_bt_kernel(const ushort* __restrict__ A,
                                                      const ushort* __restrict__ B,
                                                      void* __restrict__ Cv,
                                                      const float* __restrict__ bias,
                                                      int M, int N, int K) {
    __shared__ ushort Al[128][72];
    __shared__ ushort Bl[128][72];
    const int tid = threadIdx.x;
    const int m0 = blockIdx.y * 128, n0 = blockIdx.x * 128;
    const int lane = tid & 63, wid = tid >> 6;
    const int wm = (wid >> 1) * 64, wn = (wid & 1) * 64;
    const int lr = lane & 15, lg = lane >> 4;

    f32x4 acc[4][4];
    #pragma unroll
    for (int i = 0; i < 4; ++i)
        #pragma unroll
        for (int j = 0; j < 4; ++j)
            acc[i][j] = (f32x4){0.f, 0.f, 0.f, 0.f};

    const int arow = tid >> 3;
    const int ac8  = (tid & 7) * 8;
    const int nkt = K >> 6;
    for (int kt = 0; kt < nkt; ++kt) {
        __syncthreads();
        #pragma unroll
        for (int i = 0; i < 4; ++i) {
            int row = arow + i * 32;
            *(uint4*)&Al[row][ac8] = *(const uint4*)&A[(size_t)(m0 + row) * K + kt * 64 + ac8];
            *(uint4*)&Bl[row][ac8] = *(const uint4*)&B[(size_t)(n0 + row) * K + kt * 64 + ac8];
        }
        __syncthreads();
        #pragma unroll
        for (int kk = 0; kk < 64; kk += 32) {
            bf16x8 af[4], bfr[4];
            #pragma unroll
            for (int mi = 0; mi < 4; ++mi)
                af[mi] = *(const bf16x8*)&Al[wm + mi * 16 + lr][kk + lg * 8];
            #pragma unroll
            for (int ni = 0; ni < 4; ++ni)
                bfr[ni] = *(const bf16x8*)&Bl[wn + ni * 16 + lr][kk + lg * 8];
            #pragma unroll
            for (int mi = 0; mi < 4; ++mi)
                #pragma unroll
                for (int ni = 0; ni < 4; ++ni)
                    acc[mi][ni] = __builtin_amdgcn_mfma_f32_16x16x32_bf16(af[mi], bfr[ni], acc[mi][ni], 0, 0, 0);
        }
    }
    // epilogue: D row = (lane>>4)*4 + r, col = lane&15
    #pragma unroll
    for (int mi = 0; mi < 4; ++mi) {
        #pragma unroll
        for (int r = 0; r < 4; ++r) {
            int gm = m0 + wm + mi * 16 + lg * 4 + r;
            #pragma unroll
            for (int ni = 0; ni < 4; ++ni) {
                int gn = n0 + wn + ni * 16 + lr;
                float val = acc[mi][ni][r];
                if (BF16_OUT) {
                    ((ushort*)Cv)[(size_t)gm * N + gn] = f2b(val);
                } else {
                    ((float*)Cv)[(size_t)gm * N + gn] = val + bias[gn];
                }
            }
        }
    }
}

// ---------------- V transpose: Vt[nv][t] = QKV[t][2048+nv] ----------------
__global__ void transpose_v_kernel(const ushort* __restrict__ QKV, ushort* __restrict__ Vt) {
    __shared__ ushort tile[32][33];
    int t0 = blockIdx.x * 32;
    int n0 = blockIdx.y * 32;
    int tx = threadIdx.x, ty = threadIdx.y; // (32,8)
    #pragma unroll
    for (int i = 0; i < 4; ++i) {
        int row = ty + i * 8;
        tile[row][tx] = QKV[(size_t)(t0 + row) * 3072 + 2048 + n0 + tx];
    }
    __syncthreads();
    #pragma unroll
    for (int i = 0; i < 4; ++i) {
        int row = ty + i * 8;
        Vt[(size_t)(n0 + row) * 8192 + t0 + tx] = tile[tx][row];
    }
}

// ---------------- causal flash attention v2 ----------------
// QKV [8192][3072] bf16 (Q pre-scaled by 0.125), Vt [1024][8192] bf16, O [8192][1024] bf16
// 4 waves x 32 q-rows = 128 q-rows per block; KVBLK=64; dbuf K/V; 1 barrier/iter.
__global__ __launch_bounds__(256, 3) void attn_kernel(const ushort* __restrict__ QKV,
                                                      const ushort* __restrict__ Vt,
                                                      ushort* __restrict__ O) {
    __shared__ ushort Kl[2][64 * 64];
    __shared__ ushort Vl[2][64 * 64];
    __shared__ ushort Pl[4][32 * 64];

    const int bh = blockIdx.x, b = bh >> 4, h = bh & 15;
    const int qb = (int)gridDim.y - 1 - (int)blockIdx.y;   // heavy blocks first
    const int q0 = qb * 128;
    const int tid = threadIdx.x, lane = tid & 63, w = tid >> 6;
    const int lr = lane & 15, lg = lane >> 4;
    const int qw = q0 + w * 32;

    // Q fragments (A-frag: lane lr = q row, 8 contiguous k at lg*8): qf[mi][ks]
    bf16x8 qf[2][2];
    {
        const ushort* qp = QKV + (size_t)(b * 2048 + qw + lr) * 3072 + h * 64 + lg * 8;
        qf[0][0] = *(const bf16x8*)qp;
        qf[0][1] = *(const bf16x8*)(qp + 32);
        qf[1][0] = *(const bf16x8*)(qp + (size_t)16 * 3072);
        qf[1][1] = *(const bf16x8*)(qp + (size_t)16 * 3072 + 32);
    }

    f32x4 o[2][4];
    #pragma unroll
    for (int mi = 0; mi < 2; ++mi)
        #pragma unroll
        for (int ni = 0; ni < 4; ++ni)
            o[mi][ni] = (f32x4){0.f, 0.f, 0.f, 0.f};
    float mrow[2][4], lrow[2][4];
    #pragma unroll
    for (int mi = 0; mi < 2; ++mi)
        #pragma unroll
        for (int r = 0; r < 4; ++r) { mrow[mi][r] = -INFINITY; lrow[mi][r] = 0.f; }

    const size_t kbase = (size_t)(b * 2048) * 3072 + 1024 + h * 64;
    const size_t vbase = (size_t)(h * 64) * 8192 + (size_t)b * 2048;
    const int srow = tid >> 2, sc = tid & 3;   // 64 rows x 4 threads; chunks sc, sc+4

    const int nt = qb * 2 + 2;

    // stage tile t into buffer bufi
    #define STAGE(t, bufi) do {                                              \
        const int kv0s = (t) * 64;                                           \
        const ushort* kg = QKV + kbase + (size_t)(kv0s + srow) * 3072;       \
        const ushort* vg = Vt + vbase + (size_t)srow * 8192 + kv0s;          \
        const int s0 = swz(srow, sc), s1 = swz(srow, sc + 4);                \
        *(uint4*)&Kl[bufi][s0] = *(const uint4*)&kg[sc * 8];                 \
        *(uint4*)&Kl[bufi][s1] = *(const uint4*)&kg[sc * 8 + 32];            \
        *(uint4*)&Vl[bufi][s0] = *(const uint4*)&vg[sc * 8];                 \
        *(uint4*)&Vl[bufi][s1] = *(const uint4*)&vg[sc * 8 + 32];            \
    } while (0)

    STAGE(0, 0);
    __syncthreads();

    for (int t = 0; t < nt; ++t) {
        const int buf = t & 1;
        const int kv0 = t * 64;
        if (t + 1 < nt) STAGE(t + 1, buf ^ 1);

        if (kv0 <= qw + 31) {
            // ---- QK^T: S[32 q][64 kv] ----
            f32x4 s[2][4];
            #pragma unroll
            for (int mi = 0; mi < 2; ++mi)
                #pragma unroll
                for (int ni = 0; ni < 4; ++ni)
                    s[mi][ni] = (f32x4){0.f, 0.f, 0.f, 0.f};
            #pragma unroll
            for (int ks = 0; ks < 2; ++ks) {
                #pragma unroll
                for (int ni = 0; ni < 4; ++ni) {
                    const int row = ni * 16 + lr;
                    bf16x8 kf = *(const bf16x8*)&Kl[buf][swz(row, ks * 4 + lg)];
                    s[0][ni] = __builtin_amdgcn_mfma_f32_16x16x32_bf16(qf[0][ks], kf, s[0][ni], 0, 0, 0);
                    s[1][ni] = __builtin_amdgcn_mfma_f32_16x16x32_bf16(qf[1][ks], kf, s[1][ni], 0, 0, 0);
                }
            }
            // ---- online softmax (rows = mi*16 + lg*4 + r, cols = ni*16 + lr) ----
            #pragma unroll
            for (int mi = 0; mi < 2; ++mi) {
                const bool full = (kv0 + 63 <= qw + mi * 16);
                float alpha[4];
                #pragma unroll
                for (int r = 0; r < 4; ++r) {
                    const int qs = qw + mi * 16 + lg * 4 + r;
                    float v0 = s[mi][0][r], v1 = s[mi][1][r], v2 = s[mi][2][r], v3 = s[mi][3][r];
                    if (!full) {
                        v0 = (kv0 + lr <= qs) ? v0 : -INFINITY;
                        v1 = (kv0 + 16 + lr <= qs) ? v1 : -INFINITY;
                        v2 = (kv0 + 32 + lr <= qs) ? v2 : -INFINITY;
                        v3 = (kv0 + 48 + lr <= qs) ? v3 : -INFINITY;
                    }
                    float mx = fmaxf(fmaxf(v0, v1), fmaxf(v2, v3));
                    mx = fmaxf(mx, __shfl_xor(mx, 1));
                    mx = fmaxf(mx, __shfl_xor(mx, 2));
                    mx = fmaxf(mx, __shfl_xor(mx, 4));
                    mx = fmaxf(mx, __shfl_xor(mx, 8));
                    const float mn = fmaxf(mrow[mi][r], mx);
                    const float al = __expf(mrow[mi][r] - mn);
                    const float p0 = __expf(v0 - mn);
                    const float p1 = __expf(v1 - mn);
                    const float p2 = __expf(v2 - mn);
                    const float p3 = __expf(v3 - mn);
                    float rs = p0 + p1 + p2 + p3;
                    rs += __shfl_xor(rs, 1);
                    rs += __shfl_xor(rs, 2);
                    rs += __shfl_xor(rs, 4);
                    rs += __shfl_xor(rs, 8);
                    mrow[mi][r] = mn;
                    lrow[mi][r] = lrow[mi][r] * al + rs;
                    alpha[r] = al;
                    // write P (wave-private, same XOR involution as reads)
                    const int qr = mi * 16 + lg * 4 + r;
                    ushort* pr = &Pl[w][qr * 64];
                    const int xr = (qr & 7) << 3;
                    pr[(lr) ^ xr]        = f2b(p0);
                    pr[(16 + lr) ^ xr]   = f2b(p1);
                    pr[(32 + lr) ^ xr]   = f2b(p2);
                    pr[(48 + lr) ^ xr]   = f2b(p3);
                }
                #pragma unroll
                for (int ni = 0; ni < 4; ++ni)
                    #pragma unroll
                    for (int r = 0; r < 4; ++r) o[mi][ni][r] *= alpha[r];
            }
            // wave-private P write->read ordering (LDS is in-order per wave; drain to be safe)
            asm volatile("s_waitcnt lgkmcnt(0)" ::: "memory");
            __builtin_amdgcn_sched_barrier(0);
            // ---- PV: O[32 q][64 d] += P[32][64] * V^T ----
            #pragma unroll
            for (int ks = 0; ks < 2; ++ks) {
                bf16x8 pa[2];
                #pragma unroll
                for (int mi = 0; mi < 2; ++mi) {
                    const int row = mi * 16 + lr;
                    pa[mi] = *(const bf16x8*)&Pl[w][swz(row, ks * 4 + lg)];
                }
                #pragma unroll
                for (int ni = 0; ni < 4; ++ni) {
                    const int row = ni * 16 + lr;
                    bf16x8 vf = *(const bf16x8*)&Vl[buf][swz(row, ks * 4 + lg)];
                    o[0][ni] = __builtin_amdgcn_mfma_f32_16x16x32_bf16(pa[0], vf, o[0][ni], 0, 0, 0);
                    o[1][ni] = __builtin_amdgcn_mfma_f32_16x16x32_bf16(pa[1], vf, o[1][ni], 0, 0, 0);
                }
            }
        }
        __syncthreads();   // staging(t+1) visible; reads of buf done before t+2 overwrites
    }
    #undef STAGE

    #pragma unroll
    for (int mi = 0; mi < 2; ++mi) {
        #pragma unroll
        for (int r = 0; r < 4; ++r) {
            const float inv = 1.0f / lrow[mi][r];
            const size_t rowg = (size_t)(b * 2048 + qw + mi * 16 + lg * 4 + r) * 1024 + h * 64;
            #pragma unroll
            for (int ni = 0; ni < 4; ++ni)
                O[rowg + ni * 16 + lr] = f2b(o[mi][ni][r] * inv);
        }
    }
}

// ---------------- launch ----------------
extern "C" void kernel_launch(void* const* d_in, const int* in_sizes, int n_in,
                              void* d_out, int out_size, void* d_ws, size_t ws_size,
                              hipStream_t stream) {
    const float* x  = (const float*)d_in[0];
    const float* Wk = (const float*)d_in[1];
    const float* Wq = (const float*)d_in[2];
    const float* Wv = (const float*)d_in[3];
    const float* Wp = (const float*)d_in[4];
    const float* bp = (const float*)d_in[5];
    float* out = (float*)d_out;

    char* ws = (char*)d_ws;
    ushort* Xb   = (ushort*)(ws);                       // 8192x1024 bf16 = 16 MB
    ushort* Wcat = (ushort*)(ws + 16777216);            // 4096x1024 bf16 = 8 MB
    ushort* QKV  = (ushort*)(ws + 25165824);            // 8192x3072 bf16 = 48 MB
    ushort* Vt   = (ushort*)(ws + 75497472);            // 1024x8192 bf16 = 16 MB
    ushort* Obuf = (ushort*)(ws + 92274688);            // 8192x1024 bf16 = 16 MB

    cast_w_kernel<<<4096, 256, 0, stream>>>(Wq, Wk, Wv, Wp, Wcat);
    cast_x_kernel<<<8192, 256, 0, stream>>>(x, Xb);
    gemm_bt_kernel<true><<<dim3(24, 64), 256, 0, stream>>>(Xb, Wcat, QKV, nullptr, 8192, 3072, 1024);
    transpose_v_kernel<<<dim3(256, 32), dim3(32, 8), 0, stream>>>(QKV, Vt);
    attn_kernel<<<dim3(64, 16), 256, 0, stream>>>(QKV, Vt, Obuf);
    gemm_bt_kernel<false><<<dim3(8, 64), 256, 0, stream>>>(Obuf, Wcat + (size_t)3072 * 1024, out, bp, 8192, 1024, 1024);
}

// Round 3
// 189.396 us; speedup vs baseline: 2.3101x; 1.2555x over previous
//
#include <hip/hip_runtime.h>
#include <hip/hip_bf16.h>

typedef __attribute__((ext_vector_type(8))) short bf16x8;
typedef __attribute__((ext_vector_type(4))) float f32x4;

#define DEVINL __device__ __forceinline__

static DEVINL ushort f2b(float f) {
    union { float f; unsigned int u; } v; v.f = f;
    unsigned int u = v.u;
    unsigned int r = (u + 0x7FFFu + ((u >> 16) & 1u)) >> 16;
    return (ushort)r;
}

static DEVINL unsigned int cvtpk(float lo, float hi) {
    unsigned int r;
    asm("v_cvt_pk_bf16_f32 %0, %1, %2" : "=v"(r) : "v"(lo), "v"(hi));
    return r;
}

// swizzled ushort offset of 16B chunk c (0..7) in row of a [*][64]-bf16 linear tile
static DEVINL int swz(int row, int c) {
    return row * 64 + (((c ^ (row & 7)) & 7) << 3);
}

// ---------------- cast kernels ----------------
// Wcat[n][k], n in [0,4096): rows 0-1023 = Wq*0.125, 1024-2047 = Wk, 2048-3071 = Wv, 3072-4095 = Wp
__global__ void cast_w_kernel(const float* __restrict__ Wq, const float* __restrict__ Wk,
                              const float* __restrict__ Wv, const float* __restrict__ Wp,
                              ushort* __restrict__ out) {
    int idx = blockIdx.x * blockDim.x + threadIdx.x;   // one float4 per thread
    int col4 = idx & 255;          // 1024/4
    int row  = idx >> 8;           // 0..4095
    int which = row >> 10;
    int r = row & 1023;
    const float* src = (which == 0) ? Wq : (which == 1) ? Wk : (which == 2) ? Wv : Wp;
    float s = (which == 0) ? 0.125f : 1.0f;
    float4 v = ((const float4*)src)[r * 256 + col4];
    ushort4 o;
    o.x = f2b(v.x * s); o.y = f2b(v.y * s); o.z = f2b(v.z * s); o.w = f2b(v.w * s);
    ((ushort4*)out)[idx] = o;
}

__global__ void cast_x_kernel(const float* __restrict__ x, ushort* __restrict__ out) {
    int idx = blockIdx.x * blockDim.x + threadIdx.x;   // one float4 per thread
    float4 v = ((const float4*)x)[idx];
    ushort4 o;
    o.x = f2b(v.x); o.y = f2b(v.y); o.z = f2b(v.z); o.w = f2b(v.w);
    ((ushort4*)out)[idx] = o;
}

// ---------------- generic GEMM: C[m][n] = sum_k A[m][k]*B[n][k] (+bias) ----------------
template<bool BF16_OUT>
__global__ __launch_bounds__(256) void gemm_bt_kernel(const ushort* __restrict__ A,
                                                      const ushort* __restrict__ B,
                                                      void* __restrict__ Cv,
                                                      const float* __restrict__ bias,
                                                      int M, int N, int K) {
    __shared__ ushort Al[128][72];
    __shared__ ushort Bl[128][72];
    const int tid = threadIdx.x;
    const int m0 = blockIdx.y * 128, n0 = blockIdx.x * 128;
    const int lane = tid & 63, wid = tid >> 6;
    const int wm = (wid >> 1) * 64, wn = (wid & 1) * 64;
    const int lr = lane & 15, lg = lane >> 4;

    f32x4 acc[4][4];
    #pragma unroll
    for (int i = 0; i < 4; ++i)
        #pragma unroll
        for (int j = 0; j < 4; ++j)
            acc[i][j] = (f32x4){0.f, 0.f, 0.f, 0.f};

    const int arow = tid >> 3;
    const int ac8  = (tid & 7) * 8;
    const int nkt = K >> 6;
    for (int kt = 0; kt < nkt; ++kt) {
        __syncthreads();
        #pragma unroll
        for (int i = 0; i < 4; ++i) {
            int row = arow + i * 32;
            *(uint4*)&Al[row][ac8] = *(const uint4*)&A[(size_t)(m0 + row) * K + kt * 64 + ac8];
            *(uint4*)&Bl[row][ac8] = *(const uint4*)&B[(size_t)(n0 + row) * K + kt * 64 + ac8];
        }
        __syncthreads();
        #pragma unroll
        for (int kk = 0; kk < 64; kk += 32) {
            bf16x8 af[4], bfr[4];
            #pragma unroll
            for (int mi = 0; mi < 4; ++mi)
                af[mi] = *(const bf16x8*)&Al[wm + mi * 16 + lr][kk + lg * 8];
            #pragma unroll
            for (int ni = 0; ni < 4; ++ni)
                bfr[ni] = *(const bf16x8*)&Bl[wn + ni * 16 + lr][kk + lg * 8];
            #pragma unroll
            for (int mi = 0; mi < 4; ++mi)
                #pragma unroll
                for (int ni = 0; ni < 4; ++ni)
                    acc[mi][ni] = __builtin_amdgcn_mfma_f32_16x16x32_bf16(af[mi], bfr[ni], acc[mi][ni], 0, 0, 0);
        }
    }
    // epilogue: D row = (lane>>4)*4 + r, col = lane&15
    #pragma unroll
    for (int mi = 0; mi < 4; ++mi) {
        #pragma unroll
        for (int r = 0; r < 4; ++r) {
            int gm = m0 + wm + mi * 16 + lg * 4 + r;
            #pragma unroll
            for (int ni = 0; ni < 4; ++ni) {
                int gn = n0 + wn + ni * 16 + lr;
                float val = acc[mi][ni][r];
                if (BF16_OUT) {
                    ((ushort*)Cv)[(size_t)gm * N + gn] = f2b(val);
                } else {
                    ((float*)Cv)[(size_t)gm * N + gn] = val + bias[gn];
                }
            }
        }
    }
}

// ---------------- V transpose: Vt[nv][t] = QKV[t][2048+nv] ----------------
__global__ void transpose_v_kernel(const ushort* __restrict__ QKV, ushort* __restrict__ Vt) {
    __shared__ ushort tile[32][33];
    int t0 = blockIdx.x * 32;
    int n0 = blockIdx.y * 32;
    int tx = threadIdx.x, ty = threadIdx.y; // (32,8)
    #pragma unroll
    for (int i = 0; i < 4; ++i) {
        int row = ty + i * 8;
        tile[row][tx] = QKV[(size_t)(t0 + row) * 3072 + 2048 + n0 + tx];
    }
    __syncthreads();
    #pragma unroll
    for (int i = 0; i < 4; ++i) {
        int row = ty + i * 8;
        Vt[(size_t)(n0 + row) * 8192 + t0 + tx] = tile[tx][row];
    }
}

// ---------------- causal flash attention v3 (swapped QK^T) ----------------
// QKV [8192][3072] bf16 (Q pre-scaled by 0.125), Vt [1024][8192] bf16, O [8192][1024] bf16
// 4 waves x 32 q-rows; KVBLK=64; dbuf K/V; swapped S^T layout; O^T accumulators.
__global__ __launch_bounds__(256, 3) void attn_kernel(const ushort* __restrict__ QKV,
                                                      const ushort* __restrict__ Vt,
                                                      ushort* __restrict__ O) {
    __shared__ ushort Kl[2][64 * 64];
    __shared__ ushort Vl[2][64 * 64];
    __shared__ ushort Pl[4][32 * 64];

    const int bh = blockIdx.x, b = bh >> 4, h = bh & 15;
    const int qb = (int)gridDim.y - 1 - (int)blockIdx.y;   // heavy blocks first
    const int q0 = qb * 128;
    const int tid = threadIdx.x, lane = tid & 63, w = tid >> 6;
    const int lr = lane & 15, lg = lane >> 4;
    const int qw = q0 + w * 32;

    // Q fragments (B-frag for swapped QK^T: lane lr = q row, 8 contiguous d at lg*8)
    bf16x8 qf[2][2];   // [nt][ks]
    {
        const ushort* qp = QKV + (size_t)(b * 2048 + qw + lr) * 3072 + h * 64 + lg * 8;
        qf[0][0] = *(const bf16x8*)qp;
        qf[0][1] = *(const bf16x8*)(qp + 32);
        qf[1][0] = *(const bf16x8*)(qp + (size_t)16 * 3072);
        qf[1][1] = *(const bf16x8*)(qp + (size_t)16 * 3072 + 32);
    }

    // O^T accumulators: o[di][nt], C layout: row d = di*16+lg*4+r, col q = nt*16+lr
    f32x4 o[4][2];
    #pragma unroll
    for (int di = 0; di < 4; ++di)
        #pragma unroll
        for (int nt_ = 0; nt_ < 2; ++nt_)
            o[di][nt_] = (f32x4){0.f, 0.f, 0.f, 0.f};
    float mrow[2] = {-INFINITY, -INFINITY};
    float lrow[2] = {0.f, 0.f};

    const size_t kbase = (size_t)(b * 2048) * 3072 + 1024 + h * 64;
    const size_t vbase = (size_t)(h * 64) * 8192 + (size_t)b * 2048;
    const int srow = tid >> 2, sc = tid & 3;   // 64 rows x 4 threads; chunks sc, sc+4
    const int ss0 = swz(srow, sc), ss1 = swz(srow, sc + 4);
    char* const pw = (char*)&Pl[w][0];

    const int nt = qb * 2 + 2;
    uint4 kr0, kr1, vr0, vr1;

    #define LOADT(t) do {                                                      \
        const int kv0s = (t) * 64;                                             \
        const ushort* kg = QKV + kbase + (size_t)(kv0s + srow) * 3072;         \
        const ushort* vg = Vt + vbase + (size_t)srow * 8192 + kv0s;            \
        kr0 = *(const uint4*)&kg[sc * 8];                                      \
        kr1 = *(const uint4*)&kg[sc * 8 + 32];                                 \
        vr0 = *(const uint4*)&vg[sc * 8];                                      \
        vr1 = *(const uint4*)&vg[sc * 8 + 32];                                 \
    } while (0)

    #define WRITET(bufi) do {                                                  \
        *(uint4*)&Kl[bufi][ss0] = kr0;                                         \
        *(uint4*)&Kl[bufi][ss1] = kr1;                                         \
        *(uint4*)&Vl[bufi][ss0] = vr0;                                         \
        *(uint4*)&Vl[bufi][ss1] = vr1;                                         \
    } while (0)

    LOADT(0);
    WRITET(0);
    __syncthreads();

    for (int t = 0; t < nt; ++t) {
        const int buf = t & 1;
        const int kv0 = t * 64;
        const bool have_next = (t + 1 < nt);
        if (have_next) LOADT(t + 1);     // issue early; LDS write after PV (T14)

        if (kv0 <= qw + 31) {
            // ---- swapped QK^T: S^T[kv][q], s[mi][nt] ----
            f32x4 s[4][2];
            #pragma unroll
            for (int mi = 0; mi < 4; ++mi)
                #pragma unroll
                for (int nt_ = 0; nt_ < 2; ++nt_)
                    s[mi][nt_] = (f32x4){0.f, 0.f, 0.f, 0.f};
            __builtin_amdgcn_s_setprio(1);
            #pragma unroll
            for (int ks = 0; ks < 2; ++ks) {
                #pragma unroll
                for (int mi = 0; mi < 4; ++mi) {
                    bf16x8 kf = *(const bf16x8*)&Kl[buf][swz(mi * 16 + lr, ks * 4 + lg)];
                    s[mi][0] = __builtin_amdgcn_mfma_f32_16x16x32_bf16(kf, qf[0][ks], s[mi][0], 0, 0, 0);
                    s[mi][1] = __builtin_amdgcn_mfma_f32_16x16x32_bf16(kf, qf[1][ks], s[mi][1], 0, 0, 0);
                }
            }
            __builtin_amdgcn_s_setprio(0);

            // ---- online softmax: each lane owns q = qw + nt*16 + lr ----
            #pragma unroll
            for (int nt_ = 0; nt_ < 2; ++nt_) {
                const int qn = qw + nt_ * 16 + lr;
                const bool full = (kv0 + 63 <= qw + nt_ * 16);
                const int kvb = kv0 + lg * 4;
                float v[4][4];
                #pragma unroll
                for (int mi = 0; mi < 4; ++mi)
                    #pragma unroll
                    for (int r = 0; r < 4; ++r) {
                        float x = s[mi][nt_][r];
                        if (!full) x = (kvb + mi * 16 + r <= qn) ? x : -INFINITY;
                        v[mi][r] = x;
                    }
                // tile max (16 local + xor16 + xor32)
                float mx0 = fmaxf(fmaxf(v[0][0], v[0][1]), fmaxf(v[0][2], v[0][3]));
                float mx1 = fmaxf(fmaxf(v[1][0], v[1][1]), fmaxf(v[1][2], v[1][3]));
                float mx2 = fmaxf(fmaxf(v[2][0], v[2][1]), fmaxf(v[2][2], v[2][3]));
                float mx3 = fmaxf(fmaxf(v[3][0], v[3][1]), fmaxf(v[3][2], v[3][3]));
                float pmax = fmaxf(fmaxf(mx0, mx1), fmaxf(mx2, mx3));
                pmax = fmaxf(pmax, __shfl_xor(pmax, 16));
                pmax = fmaxf(pmax, __shfl_xor(pmax, 32));

                const bool defer = __all(pmax <= mrow[nt_] + 8.0f);
                float mn;
                if (defer) {
                    mn = mrow[nt_];
                } else {
                    mn = fmaxf(mrow[nt_], pmax);
                    const float al = __expf(mrow[nt_] - mn);
                    lrow[nt_] *= al;
                    #pragma unroll
                    for (int di = 0; di < 4; ++di)
                        #pragma unroll
                        for (int r = 0; r < 4; ++r)
                            o[di][nt_][r] *= al;
                    mrow[nt_] = mn;
                }
                float p[4][4];
                #pragma unroll
                for (int mi = 0; mi < 4; ++mi)
                    #pragma unroll
                    for (int r = 0; r < 4; ++r)
                        p[mi][r] = __expf(v[mi][r] - mn);
                float rs = ((p[0][0] + p[0][1]) + (p[0][2] + p[0][3]))
                         + ((p[1][0] + p[1][1]) + (p[1][2] + p[1][3]))
                         + ((p[2][0] + p[2][1]) + (p[2][2] + p[2][3]))
                         + ((p[3][0] + p[3][1]) + (p[3][2] + p[3][3]));
                rs += __shfl_xor(rs, 16);
                rs += __shfl_xor(rs, 32);
                lrow[nt_] += rs;

                // pack P[q][kv] pairs -> LDS (wave-private, XOR-swizzled, b64 writes)
                const int rowoff = (nt_ * 16 + lr) * 128;
                const int xr = (lr & 7) << 4;
                #pragma unroll
                for (int mi = 0; mi < 4; ++mi) {
                    uint2 val;
                    val.x = cvtpk(p[mi][0], p[mi][1]);
                    val.y = cvtpk(p[mi][2], p[mi][3]);
                    *(uint2*)(pw + rowoff + ((32 * mi + 8 * lg) ^ xr)) = val;
                }
            }
            asm volatile("s_waitcnt lgkmcnt(0)" ::: "memory");
            __builtin_amdgcn_sched_barrier(0);

            // ---- PV: O^T[d][q] += V^T[d][kv] * P^T[kv][q] ----
            __builtin_amdgcn_s_setprio(1);
            #pragma unroll
            for (int ks = 0; ks < 2; ++ks) {
                bf16x8 pb[2];
                #pragma unroll
                for (int nt_ = 0; nt_ < 2; ++nt_) {
                    const int byteoff = (nt_ * 16 + lr) * 128 + (((64 * ks + 16 * lg)) ^ ((lr & 7) << 4));
                    pb[nt_] = *(const bf16x8*)(pw + byteoff);
                }
                #pragma unroll
                for (int di = 0; di < 4; ++di) {
                    bf16x8 vf = *(const bf16x8*)&Vl[buf][swz(di * 16 + lr, ks * 4 + lg)];
                    o[di][0] = __builtin_amdgcn_mfma_f32_16x16x32_bf16(vf, pb[0], o[di][0], 0, 0, 0);
                    o[di][1] = __builtin_amdgcn_mfma_f32_16x16x32_bf16(vf, pb[1], o[di][1], 0, 0, 0);
                }
            }
            __builtin_amdgcn_s_setprio(0);
        }
        if (have_next) WRITET(buf ^ 1);   // vmcnt wait lands here, hidden under compute
        __syncthreads();
    }
    #undef LOADT
    #undef WRITET

    // ---- epilogue: normalize, transpose O^T -> O via Pl, coalesced stores ----
    #pragma unroll
    for (int nt_ = 0; nt_ < 2; ++nt_) {
        const float inv = 1.0f / lrow[nt_];
        const int rowoff = (nt_ * 16 + lr) * 128;
        const int xr = (lr & 7) << 4;
        #pragma unroll
        for (int di = 0; di < 4; ++di) {
            uint2 val;
            val.x = cvtpk(o[di][nt_][0] * inv, o[di][nt_][1] * inv);
            val.y = cvtpk(o[di][nt_][2] * inv, o[di][nt_][3] * inv);
            *(uint2*)(pw + rowoff + ((32 * di + 8 * lg) ^ xr)) = val;
        }
    }
    asm volatile("s_waitcnt lgkmcnt(0)" ::: "memory");
    __builtin_amdgcn_sched_barrier(0);
    {
        const int row = lane >> 1;          // 0..31
        const int half = lane & 1;
        const int xr2 = (row & 7) << 4;
        ushort* og = O + (size_t)(b * 2048 + qw + row) * 1024 + h * 64 + half * 32;
        #pragma unroll
        for (int c = 0; c < 4; ++c) {
            uint4 val = *(const uint4*)(pw + row * 128 + ((half * 64 + c * 16) ^ xr2));
            *(uint4*)&og[c * 8] = val;
        }
    }
}

// ---------------- launch ----------------
extern "C" void kernel_launch(void* const* d_in, const int* in_sizes, int n_in,
                              void* d_out, int out_size, void* d_ws, size_t ws_size,
                              hipStream_t stream) {
    const float* x  = (const float*)d_in[0];
    const float* Wk = (const float*)d_in[1];
    const float* Wq = (const float*)d_in[2];
    const float* Wv = (const float*)d_in[3];
    const float* Wp = (const float*)d_in[4];
    const float* bp = (const float*)d_in[5];
    float* out = (float*)d_out;

    char* ws = (char*)d_ws;
    ushort* Xb   = (ushort*)(ws);                       // 8192x1024 bf16 = 16 MB
    ushort* Wcat = (ushort*)(ws + 16777216);            // 4096x1024 bf16 = 8 MB
    ushort* QKV  = (ushort*)(ws + 25165824);            // 8192x3072 bf16 = 48 MB
    ushort* Vt   = (ushort*)(ws + 75497472);            // 1024x8192 bf16 = 16 MB
    ushort* Obuf = (ushort*)(ws + 92274688);            // 8192x1024 bf16 = 16 MB

    cast_w_kernel<<<4096, 256, 0, stream>>>(Wq, Wk, Wv, Wp, Wcat);
    cast_x_kernel<<<8192, 256, 0, stream>>>(x, Xb);
    gemm_bt_kernel<true><<<dim3(24, 64), 256, 0, stream>>>(Xb, Wcat, QKV, nullptr, 8192, 3072, 1024);
    transpose_v_kernel<<<dim3(256, 32), dim3(32, 8), 0, stream>>>(QKV, Vt);
    attn_kernel<<<dim3(64, 16), 256, 0, stream>>>(QKV, Vt, Obuf);
    gemm_bt_kernel<false><<<dim3(8, 64), 256, 0, stream>>>(Obuf, Wcat + (size_t)3072 * 1024, out, bp, 8192, 1024, 1024);
}